// Round 1
// 179.382 us; speedup vs baseline: 1.3181x; 1.3181x over previous
//
#include <hip/hip_runtime.h>
#include <hip/hip_bf16.h>

// TreeLSTM on MI355X — round 13: whole-forest fusion.
// Insight: above the leaves each tree's level chain (d7..d0) is independent and
// its entire h/c state (255 nodes x 128 feats x bf16 x {h,c}) fits in LDS.
// One workgroup per (layer,tree): 256 blocks x 512 threads = 1 block/CU.
//   - leaves computed in 32-row double-buffered LDS tiles, interleaved with d7
//     consumption (d7 mtile k eats exactly leaf rows 32k..32k+31) -> h/c NEVER
//     go to global memory; only root h/c written out.
//   - wave w owns output feats [16w,16w+16) for ALL gates; B fragments (Wi/Ui/
//     Wf/Uf, f0/f1 share cols) live in 128 VGPRs for the whole kernel.
//   - Ui*(h0+h1) done as two MFMAs (linearity) instead of VALU bf16 adds.
//   - x read directly from f32 features (inline cvt) -> no xb16, no Bg; pack
//     shrinks to weights-only (1024 blocks).
//   - activations use v_rcp_f32 instead of exact FP division.
// 2 dispatches total (was 6).

#define TS 511
#define NT 128

typedef __attribute__((ext_vector_type(8))) short short8;
typedef __attribute__((ext_vector_type(4))) float floatx4;

#define MFMA_B16 __builtin_amdgcn_mfma_f32_16x16x32_bf16

__device__ __forceinline__ unsigned short f2b(float f) {
    return __builtin_bit_cast(unsigned short, __float2bfloat16(f));
}
__device__ __forceinline__ float b2f_u(unsigned short u) {
    unsigned v = (unsigned)u << 16;
    return __builtin_bit_cast(float, v);
}
__device__ __forceinline__ float rcp_(float x) { return __builtin_amdgcn_rcpf(x); }
__device__ __forceinline__ float sig_(float x) { return rcp_(1.0f + __expf(-x)); }
__device__ __forceinline__ float tanh_(float x) {
    float a = fabsf(x);
    float t = __expf(-2.0f * a);
    return copysignf((1.0f - t) * rcp_(1.0f + t), x);
}

// ---------------- weight packing (weights + biases only) ----------------
// BgU/BgX[(l*512+col)*128+kp] col-major: cols 0..383 = Uiou/Wiou (i|o|u),
//   384..511 = Uf/Wf. bp5[(l*5+g)*128+o]: biases (g=3,4 both = bf).
__global__ void pack_b(const float* __restrict__ Wiou, const float* __restrict__ biou,
                       const float* __restrict__ Uiou, const float* __restrict__ Wf,
                       const float* __restrict__ bfv, const float* __restrict__ Uf,
                       unsigned short* __restrict__ BgU, unsigned short* __restrict__ BgX,
                       float* __restrict__ bp5) {
    int tid = blockIdx.x * 256 + threadIdx.x;   // 0..262143
    if (tid < 1280) {
        int l = tid / 640, r = tid % 640, g = r >> 7, o = r & 127;
        bp5[tid] = (g < 3) ? biou[l * 384 + r] : bfv[l * 128 + o];
    }
    if (tid < 131072) {
        int l = tid >> 16, r = tid & 65535, col = r >> 7, kp = r & 127;
        float v = (col < 384) ? Uiou[(l * 384 + col) * 128 + kp]
                              : Uf[(l * 128 + (col - 384)) * 128 + kp];
        BgU[((size_t)(l * 512 + col)) * 128 + kp] = f2b(v);
    } else if (tid < 262144) {
        int e2 = tid - 131072;
        int l = e2 >> 16, r = e2 & 65535, col = r >> 7, kp = r & 127;
        float v = (col < 384) ? Wiou[(l * 384 + col) * 128 + kp]
                              : Wf[(l * 128 + (col - 384)) * 128 + kp];
        BgX[((size_t)(l * 512 + col)) * 128 + kp] = f2b(v);
    }
}

// ---------------- whole-forest kernel ----------------
// LDS layout (halfwords, row stride 136 = 16B-aligned):
//   HH @0      : 192 rows — ring buffer of internal-node h
//                 level bases (local rows): d7:0(128) d6:128(64) d5:0(32)
//                 d4:32(16) d3:48(8) d2:56(4) d1:60(2) d0:62(1)
//   HC @26112  : 192 rows — same layout, c
//   LFH @52224 : 2 x 32 rows — leaf h staging (double-buffered)
//   LFC @60928 : 2 x 32 rows — leaf c staging
// Total 69632 hw = 139,264 B -> 1 block/CU.
__global__ __launch_bounds__(512) void forest(
        const float* __restrict__ feat, const unsigned short* __restrict__ BgU,
        const unsigned short* __restrict__ BgX, const float* __restrict__ bp5,
        float* __restrict__ out) {
    __shared__ unsigned short S[69632];
    const int HC0 = 26112, LFH0 = 52224, LFC0 = 60928;

    const int tid = threadIdx.x;
    const int l = blockIdx.x >> 7, tree = blockIdx.x & 127;
    const int lane = tid & 63, w = tid >> 6;
    const int quad = lane >> 4, l15 = lane & 15;
    const int o = w * 16 + l15;                     // this lane's output feature
    const float* xb = feat + (size_t)tree * TS * 128;
    const unsigned short* BU = BgU + (size_t)l * 512 * 128;
    const unsigned short* BX = BgX + (size_t)l * 512 * 128;

    // resident B fragments: gates i,o,u,f (f0/f1 share Wf and Uf cols)
    short8 bU[4][4], bX[4][4];
#pragma unroll
    for (int g = 0; g < 4; g++) {
        const size_t cb = (size_t)(g * 128 + o) * 128;
#pragma unroll
        for (int kbl = 0; kbl < 4; kbl++) {
            bU[g][kbl] = *(const short8*)(BU + cb + kbl * 32 + quad * 8);
            bX[g][kbl] = *(const short8*)(BX + cb + kbl * 32 + quad * 8);
        }
    }
    float bb[5];
#pragma unroll
    for (int g = 0; g < 5; g++) bb[g] = bp5[l * 640 + g * 128 + o];

    auto loadx8 = [&](int heap, int kbl) -> short8 {
        const float* p = xb + (size_t)heap * 128 + kbl * 32 + quad * 8;
        float4 u0 = *(const float4*)p;
        float4 u1 = *(const float4*)(p + 4);
        short8 r;
        r[0] = (short)f2b(u0.x); r[1] = (short)f2b(u0.y);
        r[2] = (short)f2b(u0.z); r[3] = (short)f2b(u0.w);
        r[4] = (short)f2b(u1.x); r[5] = (short)f2b(u1.y);
        r[6] = (short)f2b(u1.z); r[7] = (short)f2b(u1.w);
        return r;
    };

    short8 lxs[2][4];   // prefetched leaf-pair A fragments
    short8 axd[4];      // d7 A fragments (x rows)

    // two 16-row leaf tiles (32 leaf rows) -> leaf buffer `buf`
    auto leafload = [&](int mt) {
#pragma unroll
        for (int lm = 0; lm < 2; lm++)
#pragma unroll
            for (int kbl = 0; kbl < 4; kbl++)
                lxs[lm][kbl] = loadx8(255 + mt * 32 + lm * 16 + l15, kbl);
    };
    auto leafcomp = [&](int buf) {
        const int LB = LFH0 + buf * 4352;
        const int LCB = LFC0 + buf * 4352;
#pragma unroll
        for (int lm = 0; lm < 2; lm++) {
            floatx4 a0 = (floatx4){0.f, 0.f, 0.f, 0.f};
            floatx4 a1 = a0, a2 = a0;
#pragma unroll
            for (int kbl = 0; kbl < 4; kbl++) {
                a0 = MFMA_B16(lxs[lm][kbl], bX[0][kbl], a0, 0, 0, 0);
                a1 = MFMA_B16(lxs[lm][kbl], bX[1][kbl], a1, 0, 0, 0);
                a2 = MFMA_B16(lxs[lm][kbl], bX[2][kbl], a2, 0, 0, 0);
            }
#pragma unroll
            for (int r = 0; r < 4; r++) {
                float iv = sig_(a0[r] + bb[0]);
                float ov = sig_(a1[r] + bb[1]);
                float uv = tanh_(a2[r] + bb[2]);
                float cn = iv * uv;
                float hn = ov * tanh_(cn);
                int lr = lm * 16 + quad * 4 + r;
                S[LB + lr * 136 + o] = f2b(hn);
                S[LCB + lr * 136 + o] = f2b(cn);
            }
        }
    };
    // d7 mtile: 16 nodes heap 127+16mt+row, children in leaf buffer rows 2r,2r+1
    auto d7comp = [&](int mt, int buf) {
        const int LB = LFH0 + buf * 4352;
        const int LCB = LFC0 + buf * 4352;
        floatx4 ac0 = (floatx4){0.f, 0.f, 0.f, 0.f};
        floatx4 ac1 = ac0, ac2 = ac0, ac3 = ac0, ac4 = ac0;
#pragma unroll
        for (int kbl = 0; kbl < 4; kbl++) {
            short8 h0 = *(const short8*)&S[LB + (2 * l15) * 136 + kbl * 32 + quad * 8];
            short8 h1 = *(const short8*)&S[LB + (2 * l15 + 1) * 136 + kbl * 32 + quad * 8];
            short8 ax = axd[kbl];
            ac0 = MFMA_B16(ax, bX[0][kbl], ac0, 0, 0, 0);
            ac0 = MFMA_B16(h0, bU[0][kbl], ac0, 0, 0, 0);
            ac0 = MFMA_B16(h1, bU[0][kbl], ac0, 0, 0, 0);
            ac1 = MFMA_B16(ax, bX[1][kbl], ac1, 0, 0, 0);
            ac1 = MFMA_B16(h0, bU[1][kbl], ac1, 0, 0, 0);
            ac1 = MFMA_B16(h1, bU[1][kbl], ac1, 0, 0, 0);
            ac2 = MFMA_B16(ax, bX[2][kbl], ac2, 0, 0, 0);
            ac2 = MFMA_B16(h0, bU[2][kbl], ac2, 0, 0, 0);
            ac2 = MFMA_B16(h1, bU[2][kbl], ac2, 0, 0, 0);
            ac3 = MFMA_B16(ax, bX[3][kbl], ac3, 0, 0, 0);
            ac3 = MFMA_B16(h0, bU[3][kbl], ac3, 0, 0, 0);
            ac4 = MFMA_B16(ax, bX[3][kbl], ac4, 0, 0, 0);
            ac4 = MFMA_B16(h1, bU[3][kbl], ac4, 0, 0, 0);
        }
#pragma unroll
        for (int r = 0; r < 4; r++) {
            int rE = quad * 4 + r;
            float iv = sig_(ac0[r] + bb[0]);
            float ov = sig_(ac1[r] + bb[1]);
            float uv = tanh_(ac2[r] + bb[2]);
            float f0 = sig_(ac3[r] + bb[3]);
            float f1 = sig_(ac4[r] + bb[4]);
            float c0 = b2f_u(S[LCB + (2 * rE) * 136 + o]);
            float c1 = b2f_u(S[LCB + (2 * rE + 1) * 136 + o]);
            float cn = iv * uv + f0 * c0 + f1 * c1;
            float hn = ov * tanh_(cn);
            int sr = mt * 16 + rE;                  // d7 local row (base 0)
            S[sr * 136 + o] = f2b(hn);
            S[HC0 + sr * 136 + o] = f2b(cn);
        }
    };

    // ---- leaves + d7, interleaved with double-buffered leaf staging ----
    leafload(0);
    leafcomp(0);
    __syncthreads();
#pragma unroll 1
    for (int mt = 0; mt < 8; mt++) {
#pragma unroll
        for (int kbl = 0; kbl < 4; kbl++) axd[kbl] = loadx8(127 + mt * 16 + l15, kbl);
        if (mt < 7) leafload(mt + 1);               // loads in flight over d7 MFMAs
        d7comp(mt, mt & 1);
        if (mt < 7) leafcomp((mt + 1) & 1);
        __syncthreads();
    }

    // ---- levels d6..d0, all state in LDS ring buffer ----
#pragma unroll
    for (int dd = 6; dd >= 0; dd--) {
        const int nd = 1 << dd;
        const int selfB = (dd == 6) ? 128 : 64 - 2 * nd;
        const int chB = (dd == 6) ? 0 : ((dd == 5) ? 128 : 64 - 4 * nd);
        const int mts = (nd + 15) >> 4;
#pragma unroll
        for (int mt = 0; mt < mts; mt++) {
            const int rloc = (l15 < nd) ? (mt * 16 + l15) : (nd - 1);  // clamp tiny lvls
            const int heap = nd - 1 + rloc;
            floatx4 ac0 = (floatx4){0.f, 0.f, 0.f, 0.f};
            floatx4 ac1 = ac0, ac2 = ac0, ac3 = ac0, ac4 = ac0;
#pragma unroll
            for (int kbl = 0; kbl < 4; kbl++) {
                short8 ax = loadx8(heap, kbl);
                short8 h0 = *(const short8*)&S[(chB + 2 * rloc) * 136 + kbl * 32 + quad * 8];
                short8 h1 = *(const short8*)&S[(chB + 2 * rloc + 1) * 136 + kbl * 32 + quad * 8];
                ac0 = MFMA_B16(ax, bX[0][kbl], ac0, 0, 0, 0);
                ac0 = MFMA_B16(h0, bU[0][kbl], ac0, 0, 0, 0);
                ac0 = MFMA_B16(h1, bU[0][kbl], ac0, 0, 0, 0);
                ac1 = MFMA_B16(ax, bX[1][kbl], ac1, 0, 0, 0);
                ac1 = MFMA_B16(h0, bU[1][kbl], ac1, 0, 0, 0);
                ac1 = MFMA_B16(h1, bU[1][kbl], ac1, 0, 0, 0);
                ac2 = MFMA_B16(ax, bX[2][kbl], ac2, 0, 0, 0);
                ac2 = MFMA_B16(h0, bU[2][kbl], ac2, 0, 0, 0);
                ac2 = MFMA_B16(h1, bU[2][kbl], ac2, 0, 0, 0);
                ac3 = MFMA_B16(ax, bX[3][kbl], ac3, 0, 0, 0);
                ac3 = MFMA_B16(h0, bU[3][kbl], ac3, 0, 0, 0);
                ac4 = MFMA_B16(ax, bX[3][kbl], ac4, 0, 0, 0);
                ac4 = MFMA_B16(h1, bU[3][kbl], ac4, 0, 0, 0);
            }
#pragma unroll
            for (int r = 0; r < 4; r++) {
                int rE = mt * 16 + quad * 4 + r;
                if (rE < nd) {
                    float iv = sig_(ac0[r] + bb[0]);
                    float ov = sig_(ac1[r] + bb[1]);
                    float uv = tanh_(ac2[r] + bb[2]);
                    float f0 = sig_(ac3[r] + bb[3]);
                    float f1 = sig_(ac4[r] + bb[4]);
                    float c0 = b2f_u(S[HC0 + (chB + 2 * rE) * 136 + o]);
                    float c1 = b2f_u(S[HC0 + (chB + 2 * rE + 1) * 136 + o]);
                    float cn = iv * uv + f0 * c0 + f1 * c1;
                    float hn = ov * tanh_(cn);
                    S[(selfB + rE) * 136 + o] = f2b(hn);
                    S[HC0 + (selfB + rE) * 136 + o] = f2b(cn);
                    if (dd == 0) {
                        out[((size_t)l * 128 + tree) * 128 + o] = hn;
                        out[32768 + ((size_t)l * 128 + tree) * 128 + o] = cn;
                    }
                }
            }
        }
        __syncthreads();
    }
}

extern "C" void kernel_launch(void* const* d_in, const int* in_sizes, int n_in,
                              void* d_out, int out_size, void* d_ws, size_t ws_size,
                              hipStream_t stream) {
    const float* feat = (const float*)d_in[0];
    const float* Wiou = (const float*)d_in[1];
    const float* biou = (const float*)d_in[2];
    const float* Uiou = (const float*)d_in[3];
    const float* Wf   = (const float*)d_in[4];
    const float* bfv  = (const float*)d_in[5];
    const float* Uf   = (const float*)d_in[6];
    float* out = (float*)d_out;

    // ws: BgU[131072] BgX[131072] (bf16 shorts), bp5[1280] f32  (~0.53 MB)
    unsigned short* BgU = (unsigned short*)d_ws;
    unsigned short* BgX = BgU + (size_t)131072;
    float* bp5 = (float*)(BgX + (size_t)131072);

    pack_b<<<1024, 256, 0, stream>>>(Wiou, biou, Uiou, Wf, bfv, Uf, BgU, BgX, bp5);
    forest<<<256, 512, 0, stream>>>(feat, BgU, BgX, bp5, out);
}

// Round 2
// 157.634 us; speedup vs baseline: 1.5000x; 1.1380x over previous
//
#include <hip/hip_runtime.h>
#include <hip/hip_bf16.h>

// TreeLSTM on MI355X — round 14: whole-forest fusion v2 (latency attack).
// Changes vs round 13 (108 us forest):
//  - xb16: features pre-converted to bf16 in pack_b; forest A-fragments are a
//    single 16B global load (no per-use f32->bf16 VALU chains in the chain).
//  - leaf phase re-pipelined: iteration = { ltile x2 (NEXT pair -> other buf),
//    itile (current d7 tile, reads current buf) } with ONE lds-only barrier.
//    ltile loads/MFMAs overlap itile MFMAs (independent) -> ~2x work in flight.
//  - Wf*x MFMA computed once (awx) and shared by f0/f1 (13->12 MFMA/kbl).
//  - barriers drain lgkmcnt only (raw s_barrier): global loads stay in flight.
//  - __launch_bounds__(512,2): 256-VGPR budget for cross-tile scheduling.

#define TS 511
#define NT 128
#define NN (NT * TS)   // 65408

typedef __attribute__((ext_vector_type(8))) short short8;
typedef __attribute__((ext_vector_type(4))) float floatx4;

#define MFMA_B16 __builtin_amdgcn_mfma_f32_16x16x32_bf16

// LDS-only barrier: LDS writes visible, global loads NOT drained.
#define BARLDS() do { \
    asm volatile("s_waitcnt lgkmcnt(0)" ::: "memory"); \
    __builtin_amdgcn_s_barrier(); \
    asm volatile("" ::: "memory"); \
} while (0)

__device__ __forceinline__ unsigned short f2b(float f) {
    return __builtin_bit_cast(unsigned short, __float2bfloat16(f));
}
__device__ __forceinline__ float b2f_u(unsigned short u) {
    unsigned v = (unsigned)u << 16;
    return __builtin_bit_cast(float, v);
}
__device__ __forceinline__ float rcp_(float x) { return __builtin_amdgcn_rcpf(x); }
__device__ __forceinline__ float sig_(float x) { return rcp_(1.0f + __expf(-x)); }
__device__ __forceinline__ float tanh_(float x) {
    float a = fabsf(x);
    float t = __expf(-2.0f * a);
    return copysignf((1.0f - t) * rcp_(1.0f + t), x);
}

// ---------------- weight packing + x conversion ----------------
// BgU/BgX[(l*512+col)*128+kp] col-major: cols 0..383 = Uiou/Wiou (i|o|u),
//   384..511 = Uf/Wf. bp5[(l*5+g)*128+o]: biases. xb[node*128+k]: bf16 feats.
__global__ void pack_b(const float* __restrict__ Wiou, const float* __restrict__ biou,
                       const float* __restrict__ Uiou, const float* __restrict__ Wf,
                       const float* __restrict__ bfv, const float* __restrict__ Uf,
                       const float* __restrict__ feat,
                       unsigned short* __restrict__ BgU, unsigned short* __restrict__ BgX,
                       float* __restrict__ bp5, unsigned short* __restrict__ xb) {
    int tid = blockIdx.x * 256 + threadIdx.x;   // 0..1308671
    if (tid < 1280) {
        int l = tid / 640, r = tid % 640, g = r >> 7, o = r & 127;
        bp5[tid] = (g < 3) ? biou[l * 384 + r] : bfv[l * 128 + o];
    }
    if (tid < 131072) {
        int l = tid >> 16, r = tid & 65535, col = r >> 7, kp = r & 127;
        float v = (col < 384) ? Uiou[(l * 384 + col) * 128 + kp]
                              : Uf[(l * 128 + (col - 384)) * 128 + kp];
        BgU[((size_t)(l * 512 + col)) * 128 + kp] = f2b(v);
    } else if (tid < 262144) {
        int e2 = tid - 131072;
        int l = e2 >> 16, r = e2 & 65535, col = r >> 7, kp = r & 127;
        float v = (col < 384) ? Wiou[(l * 384 + col) * 128 + kp]
                              : Wf[(l * 128 + (col - 384)) * 128 + kp];
        BgX[((size_t)(l * 512 + col)) * 128 + kp] = f2b(v);
    } else {
        int e = tid - 262144;                  // < 1046528, 8 elems each
        size_t base = (size_t)e * 8;
        float4 v0 = *(const float4*)(feat + base);
        float4 v1 = *(const float4*)(feat + base + 4);
        short8 r;
        r[0] = (short)f2b(v0.x); r[1] = (short)f2b(v0.y);
        r[2] = (short)f2b(v0.z); r[3] = (short)f2b(v0.w);
        r[4] = (short)f2b(v1.x); r[5] = (short)f2b(v1.y);
        r[6] = (short)f2b(v1.z); r[7] = (short)f2b(v1.w);
        *(short8*)(xb + base) = r;
    }
}

// ---------------- whole-forest kernel ----------------
// LDS (halfwords, row stride 136):
//   h-space rows 0..191 @S[0]: internal-node h ring
//     (d7:0..127, d6:128..191, d5:0..31, d4:32..47, d3:48..55, d2:56..59,
//      d1:60..61, d0:62)
//   c-space rows 0..191 @S[HC0=26112]: same ring, c
//   leaf h: h-space rows 384+b*32+r  (buf b=0,1; 32 rows each) @S[52224..]
//   leaf c: c-space rows 256+b*32+r                            @S[60928..]
// Total 69632 hw = 139264 B -> 1 block/CU.
__global__ __launch_bounds__(512, 2) void forest(
        const unsigned short* __restrict__ xb16, const unsigned short* __restrict__ BgU,
        const unsigned short* __restrict__ BgX, const float* __restrict__ bp5,
        float* __restrict__ out) {
    __shared__ __align__(16) unsigned short S[69632];
    const int HC0 = 26112;

    const int tid = threadIdx.x;
    const int l = blockIdx.x >> 7, tree = blockIdx.x & 127;
    const int lane = tid & 63, w = tid >> 6;
    const int quad = lane >> 4, l15 = lane & 15;
    const int o = w * 16 + l15;                     // this lane's output feature
    const unsigned short* xb = xb16 + (size_t)tree * TS * 128;
    const unsigned short* BU = BgU + (size_t)l * 512 * 128;
    const unsigned short* BX = BgX + (size_t)l * 512 * 128;

    // resident B fragments: gates i,o,u,f (f0/f1 share Wf and Uf cols)
    short8 bU[4][4], bX[4][4];
#pragma unroll
    for (int g = 0; g < 4; g++) {
        const size_t cb = (size_t)(g * 128 + o) * 128;
#pragma unroll
        for (int kbl = 0; kbl < 4; kbl++) {
            bU[g][kbl] = *(const short8*)(BU + cb + kbl * 32 + quad * 8);
            bX[g][kbl] = *(const short8*)(BX + cb + kbl * 32 + quad * 8);
        }
    }
    float bb[5];
#pragma unroll
    for (int g = 0; g < 5; g++) bb[g] = bp5[l * 640 + g * 128 + o];

    auto ldx = [&](int heap, int kbl) -> short8 {
        return *(const short8*)(xb + (size_t)heap * 128 + kbl * 32 + quad * 8);
    };

    // 16-row leaf tile: x-only gates, h/c -> leaf buffer rows
    auto ltile = [&](int heapA, int selfH, int selfC) {
        floatx4 ai = (floatx4){0.f, 0.f, 0.f, 0.f};
        floatx4 ao = ai, au = ai;
#pragma unroll
        for (int kbl = 0; kbl < 4; kbl++) {
            short8 ax = ldx(heapA, kbl);
            ai = MFMA_B16(ax, bX[0][kbl], ai, 0, 0, 0);
            ao = MFMA_B16(ax, bX[1][kbl], ao, 0, 0, 0);
            au = MFMA_B16(ax, bX[2][kbl], au, 0, 0, 0);
        }
#pragma unroll
        for (int r = 0; r < 4; r++) {
            int idx = quad * 4 + r;
            float iv = sig_(ai[r] + bb[0]);
            float ov = sig_(ao[r] + bb[1]);
            float uv = tanh_(au[r] + bb[2]);
            float cn = iv * uv;
            float hn = ov * tanh_(cn);
            S[(selfH + idx) * 136 + o] = f2b(hn);
            S[HC0 + (selfC + idx) * 136 + o] = f2b(cn);
        }
    };

    // 16-node internal tile. chAh: per-lane child0 h-space row (A-side);
    // chRBc: c-space row base of children (epilogue); selfRB: own h/c row base.
    auto itile = [&](int heapA, int chAh, int selfRB, int chRBc,
                     int nValid, bool isRoot) {
        floatx4 ai = (floatx4){0.f, 0.f, 0.f, 0.f};
        floatx4 ao = ai, au = ai, awx = ai, af0 = ai, af1 = ai;
#pragma unroll
        for (int kbl = 0; kbl < 4; kbl++) {
            short8 h0 = *(const short8*)&S[chAh * 136 + kbl * 32 + quad * 8];
            short8 h1 = *(const short8*)&S[(chAh + 1) * 136 + kbl * 32 + quad * 8];
            short8 ax = ldx(heapA, kbl);
            ai = MFMA_B16(h0, bU[0][kbl], ai, 0, 0, 0);
            ai = MFMA_B16(h1, bU[0][kbl], ai, 0, 0, 0);
            ao = MFMA_B16(h0, bU[1][kbl], ao, 0, 0, 0);
            ao = MFMA_B16(h1, bU[1][kbl], ao, 0, 0, 0);
            au = MFMA_B16(h0, bU[2][kbl], au, 0, 0, 0);
            au = MFMA_B16(h1, bU[2][kbl], au, 0, 0, 0);
            af0 = MFMA_B16(h0, bU[3][kbl], af0, 0, 0, 0);
            af1 = MFMA_B16(h1, bU[3][kbl], af1, 0, 0, 0);
            ai = MFMA_B16(ax, bX[0][kbl], ai, 0, 0, 0);
            ao = MFMA_B16(ax, bX[1][kbl], ao, 0, 0, 0);
            au = MFMA_B16(ax, bX[2][kbl], au, 0, 0, 0);
            awx = MFMA_B16(ax, bX[3][kbl], awx, 0, 0, 0);
        }
#pragma unroll
        for (int r = 0; r < 4; r++) {
            int idx = quad * 4 + r;
            if (idx < nValid) {
                float iv = sig_(ai[r] + bb[0]);
                float ov = sig_(ao[r] + bb[1]);
                float uv = tanh_(au[r] + bb[2]);
                float f0 = sig_(awx[r] + af0[r] + bb[3]);
                float f1 = sig_(awx[r] + af1[r] + bb[4]);
                float c0 = b2f_u(S[HC0 + (chRBc + 2 * idx) * 136 + o]);
                float c1 = b2f_u(S[HC0 + (chRBc + 2 * idx + 1) * 136 + o]);
                float cn = iv * uv + f0 * c0 + f1 * c1;
                float hn = ov * tanh_(cn);
                S[(selfRB + idx) * 136 + o] = f2b(hn);
                S[HC0 + (selfRB + idx) * 136 + o] = f2b(cn);
                if (isRoot) {
                    out[((size_t)l * 128 + tree) * 128 + o] = hn;
                    out[32768 + ((size_t)l * 128 + tree) * 128 + o] = cn;
                }
            }
        }
    };

    // ---- leaves + d7: double-buffered, ltile(next) overlaps itile(cur) ----
    // prologue: leaf pair 0 -> buf 0
#pragma unroll
    for (int s = 0; s < 2; s++)
        ltile(255 + s * 16 + l15, 384 + s * 16, 256 + s * 16);
    BARLDS();

#pragma unroll 2
    for (int t = 0; t < 8; t++) {
        if (t < 7) {
            int b2 = (t + 1) & 1;
#pragma unroll
            for (int s = 0; s < 2; s++)
                ltile(255 + (t + 1) * 32 + s * 16 + l15,
                      384 + b2 * 32 + s * 16, 256 + b2 * 32 + s * 16);
        }
        int b = t & 1;
        itile(127 + t * 16 + l15,        // d7 node rows (heap 127..254)
              384 + b * 32 + 2 * l15,    // child h in leaf buf
              t * 16,                    // own rows: d7 region 0..127
              256 + b * 32,              // child c in leaf buf
              16, false);
        BARLDS();
    }

    // ---- levels d6..d0, state in the LDS ring ----
#pragma unroll
    for (int dd = 6; dd >= 0; dd--) {
        const int nd = 1 << dd;
        const int selfB = (dd == 6) ? 128 : 64 - 2 * nd;
        const int chB = (dd == 6) ? 0 : ((dd == 5) ? 128 : 64 - 4 * nd);
        const int mts = (nd + 15) >> 4;
#pragma unroll
        for (int mt = 0; mt < mts; mt++) {
            int rl = mt * 16 + l15;
            if (rl > nd - 1) rl = nd - 1;        // clamp tiny levels
            int nv = nd - mt * 16;
            if (nv > 16) nv = 16;
            itile(nd - 1 + rl,                   // heap row
                  chB + 2 * rl,                  // child h row
                  selfB + mt * 16,
                  chB + 2 * mt * 16,             // child c row base
                  nv, dd == 0);
        }
        BARLDS();
    }
}

extern "C" void kernel_launch(void* const* d_in, const int* in_sizes, int n_in,
                              void* d_out, int out_size, void* d_ws, size_t ws_size,
                              hipStream_t stream) {
    const float* feat = (const float*)d_in[0];
    const float* Wiou = (const float*)d_in[1];
    const float* biou = (const float*)d_in[2];
    const float* Uiou = (const float*)d_in[3];
    const float* Wf   = (const float*)d_in[4];
    const float* bfv  = (const float*)d_in[5];
    const float* Uf   = (const float*)d_in[6];
    float* out = (float*)d_out;

    // ws: BgU[131072] BgX[131072] xb16[NN*128] (bf16 shorts), bp5[1280] f32 (~17.3 MB)
    unsigned short* BgU = (unsigned short*)d_ws;
    unsigned short* BgX = BgU + (size_t)131072;
    unsigned short* xb16 = BgX + (size_t)131072;
    float* bp5 = (float*)(xb16 + (size_t)NN * 128);

    pack_b<<<5112, 256, 0, stream>>>(Wiou, biou, Uiou, Wf, bfv, Uf, feat,
                                     BgU, BgX, bp5, xb16);
    forest<<<256, 512, 0, stream>>>(xb16, BgU, BgX, bp5, out);
}